// Round 7
// baseline (493.406 us; speedup 1.0000x reference)
//
#include <hip/hip_runtime.h>
#include <hip/hip_fp16.h>

// Problem constants (from reference)
#define Nn 50000
#define Ee 1600000
#define INC 128
#define HID 128
#define OUTC 64
#define NPART 8

typedef __attribute__((ext_vector_type(8))) short short8;
typedef __attribute__((ext_vector_type(4))) float f32x4;
typedef unsigned short ushort;

// ---------------------------------------------------------------------------
// bf16 split helpers (RNE)
// ---------------------------------------------------------------------------
__device__ __forceinline__ ushort f32_to_bf16(float f) {
    unsigned u = __builtin_bit_cast(unsigned, f);
    unsigned r = u + 0x7FFFu + ((u >> 16) & 1u);
    return (ushort)(r >> 16);
}
__device__ __forceinline__ float bf16_to_f32(ushort h) {
    unsigned u = ((unsigned)h) << 16;
    return __builtin_bit_cast(float, u);
}

// ---------------------------------------------------------------------------
// CSR build: per-XCD-partition hist (returns rank) -> scan -> atomic-free fill
// counts8[p][i]: partition p = blockIdx%8. Under round-robin block->XCD
// dispatch each partition's lines stay in ONE L2 -> no cross-XCD atomic
// line bouncing. Correctness does NOT depend on the mapping (p is just a
// partition index; ranks are unique within (p,dst) and pbase8 ranges are
// disjoint).
// ---------------------------------------------------------------------------

__global__ void hist_rank_kernel(const int* __restrict__ dst, int* __restrict__ counts8,
                                 int* __restrict__ rank) {
    int e = blockIdx.x * blockDim.x + threadIdx.x;
    int p = blockIdx.x & (NPART - 1);
    if (e < Ee) rank[e] = atomicAdd(&counts8[p * Nn + dst[e]], 1);
}

__global__ void scan1_kernel(const int* __restrict__ counts8, int* __restrict__ offsets,
                             int* __restrict__ partials) {
    __shared__ int sd[256];
    int t = threadIdx.x;
    int i = blockIdx.x * 256 + t;
    int c = 0;
    if (i < Nn) {
        #pragma unroll
        for (int p = 0; p < NPART; ++p) c += counts8[p * Nn + i];
    }
    int v = c;
    #pragma unroll
    for (int off = 1; off < 256; off <<= 1) {
        sd[t] = v; __syncthreads();
        int add = (t >= off) ? sd[t - off] : 0;
        __syncthreads();
        v += add;
    }
    if (i < Nn) offsets[i] = v - c;
    if (t == 255) partials[blockIdx.x] = v;
}

// scan3: fold scan2 in (block base = sum of partials[0..blk)), then emit
// per-partition bases pbase8[p][i] and dis[i].
__global__ void scan3_kernel(int* __restrict__ offsets, const int* __restrict__ partials,
                             const int* __restrict__ counts8, int* __restrict__ pbase8,
                             float* __restrict__ dis) {
    __shared__ int sd[256];
    int t = threadIdx.x;
    int s = (t < blockIdx.x) ? partials[t] : 0;   // blockIdx.x <= 195 < 256
    sd[t] = s; __syncthreads();
    #pragma unroll
    for (int off = 128; off > 0; off >>= 1) {
        if (t < off) sd[t] += sd[t + off];
        __syncthreads();
    }
    int base = sd[0];
    int i = blockIdx.x * 256 + t;
    if (i == 0) offsets[Nn] = Ee;
    if (i < Nn) {
        int off = offsets[i] + base;
        offsets[i] = off;
        int running = off;
        #pragma unroll
        for (int p = 0; p < NPART; ++p) {
            pbase8[p * Nn + i] = running;
            running += counts8[p * Nn + i];
        }
        dis[i] = rsqrtf((float)(running - off + 1));  // deg+1 (self-loop)
    }
}

// Atomic-free scatter: pos = pbase8[p][dst] + rank, p recomputed from block id.
__global__ void fill_csr_rank(const int* __restrict__ ei, const int* __restrict__ rank,
                              const int* __restrict__ pbase8, int* __restrict__ csr) {
    int e = blockIdx.x * blockDim.x + threadIdx.x;
    int p = blockIdx.x & (NPART - 1);
    if (e < Ee) {
        int d = ei[Ee + e];
        csr[pbase8[p * Nn + d] + rank[e]] = ei[e];
    }
}

// ---------------------------------------------------------------------------
// Weight prep: split all 4 weight matrices into bf16 hi/lo planes.
// ---------------------------------------------------------------------------
__global__ void prep_w_kernel(const float* __restrict__ W1, const float* __restrict__ Wc,
                              const float* __restrict__ W2, const float* __restrict__ Wo,
                              ushort* __restrict__ base) {
    int i = blockIdx.x * 256 + threadIdx.x;  // 0..81919
    const float* src; ushort* hi; ushort* lo; int idx;
    if (i < 16384)      { src = W1; hi = base;          lo = base + 16384;  idx = i; }
    else if (i < 49152) { src = Wc; hi = base + 32768;  lo = base + 65536;  idx = i - 16384; }
    else if (i < 65536) { src = W2; hi = base + 98304;  lo = base + 114688; idx = i - 49152; }
    else                { src = Wo; hi = base + 131072; lo = base + 147456; idx = i - 65536; }
    float f = src[idx];
    ushort hb = f32_to_bf16(f);
    float  hf = bf16_to_f32(hb);
    hi[idx] = hb;
    lo[idx] = f32_to_bf16(f - hf);
}

// ---------------------------------------------------------------------------
// MFMA GEMM: OUT[N][CO] = act(concat(A0,A1)[N][K] @ W^T + bias) (* dis[row])
// W as bf16 hi/lo planes; C = Ahi*Bhi + Ahi*Blo + Alo*Bhi (rel err ~2^-17).
// Block = 512 thr / 8 waves: wave = (rowgrp 0..3, colhalf 0..1); each wave
// owns 16 rows x CO/2 cols -> 6256 waves (~24/CU) for latency hiding.
// OUTHALF: write fp16 rows (for propagate gather input).
// ---------------------------------------------------------------------------
template <int CO, int K, bool RELU, bool HASBIAS, bool SCALEDIS, bool OUTHALF>
__global__ __launch_bounds__(512) void mfma_gemm(
    const float* __restrict__ A0, const float* __restrict__ A1,
    const ushort* __restrict__ Whi, const ushort* __restrict__ Wlo,
    const float* __restrict__ bias, const float* __restrict__ dis,
    void* __restrict__ outp) {
    constexpr int NF = CO / 32;            // col fragments per wave (half CO)
    int wave   = threadIdx.x >> 6;         // 0..7
    int rowgrp = wave >> 1;                // 0..3
    int chalf  = wave & 1;                 // 0..1
    int lane = threadIdx.x & 63;
    int c = lane & 15;        // A row offset / D col offset
    int g = lane >> 4;        // k-group / D row-group
    int row0 = blockIdx.x * 64 + rowgrp * 16;
    int arow = row0 + c;
    int ar = (arow < Nn) ? arow : (Nn - 1);
    constexpr int CB = CO / 2;             // col base stride

    f32x4 acc[NF];
    #pragma unroll
    for (int f = 0; f < NF; ++f) acc[f] = (f32x4){0.f, 0.f, 0.f, 0.f};

    #pragma unroll
    for (int ks = 0; ks < K / 32; ++ks) {
        int k0 = ks * 32;
        const float* Asrc = (K == 256 && k0 >= 128) ? A1 : A0;
        int kb = (K == 256 && k0 >= 128) ? (k0 - 128) : k0;
        const float* ap = Asrc + (size_t)ar * 128 + kb + g * 8;
        float4 v0 = *(const float4*)ap;
        float4 v1 = *(const float4*)(ap + 4);
        float vv[8] = {v0.x, v0.y, v0.z, v0.w, v1.x, v1.y, v1.z, v1.w};
        short8 ahi, alo;
        #pragma unroll
        for (int j = 0; j < 8; ++j) {
            float f = vv[j];
            ushort hb = f32_to_bf16(f);
            float  hf = bf16_to_f32(hb);
            ahi[j] = (short)hb;
            alo[j] = (short)f32_to_bf16(f - hf);
        }
        int wk = k0 + g * 8;
        #pragma unroll
        for (int f = 0; f < NF; ++f) {
            size_t widx = (size_t)(chalf * CB + f * 16 + c) * K + wk;
            short8 bh = *(const short8*)(Whi + widx);
            short8 bl = *(const short8*)(Wlo + widx);
            acc[f] = __builtin_amdgcn_mfma_f32_16x16x32_bf16(alo, bh, acc[f], 0, 0, 0);
            acc[f] = __builtin_amdgcn_mfma_f32_16x16x32_bf16(ahi, bl, acc[f], 0, 0, 0);
            acc[f] = __builtin_amdgcn_mfma_f32_16x16x32_bf16(ahi, bh, acc[f], 0, 0, 0);
        }
    }

    #pragma unroll
    for (int f = 0; f < NF; ++f) {
        int col = chalf * CB + f * 16 + c;
        float bv = HASBIAS ? bias[col] : 0.f;
        #pragma unroll
        for (int rg = 0; rg < 4; ++rg) {
            int row = row0 + g * 4 + rg;
            if (row < Nn) {
                float v = acc[f][rg] + bv;
                if (RELU) v = fmaxf(v, 0.f);
                if (SCALEDIS) v *= dis[row];
                size_t idx = (size_t)row * CO + col;
                if (OUTHALF) ((__half*)outp)[idx] = __float2half_rn(v);
                else         ((float*)outp)[idx]  = v;
            }
        }
    }
}

// ---------------------------------------------------------------------------
// Propagation in g-form, fp16 gather rows (256B/row):
// out[d] = act(dis[d] * (g[d] + sum_{s in N(d)} g[s]) + bias)   [f32 out]
// One 64-lane wave per node, __half2/lane, edge loop unrolled x8.
// ---------------------------------------------------------------------------
template <bool RELU>
__global__ __launch_bounds__(256) void propagate_kernel(
    const __half* __restrict__ gbuf, const int* __restrict__ offs,
    const int* __restrict__ csr, const float* __restrict__ dis,
    const float* __restrict__ bias, float* __restrict__ out) {
    int node = blockIdx.x * 4 + (threadIdx.x >> 6);
    if (node >= Nn) return;
    int lane = threadIdx.x & 63;
    float2 sv = __half22float2(*((const __half2*)(gbuf + ((size_t)node << 7)) + lane));
    float ax = sv.x, ay = sv.y;
    int beg = offs[node], end = offs[node + 1];
    int e = beg;
    for (; e + 8 <= end; e += 8) {
        int s0 = csr[e],     s1 = csr[e + 1], s2 = csr[e + 2], s3 = csr[e + 3];
        int s4 = csr[e + 4], s5 = csr[e + 5], s6 = csr[e + 6], s7 = csr[e + 7];
        __half2 h0 = *((const __half2*)(gbuf + ((size_t)s0 << 7)) + lane);
        __half2 h1 = *((const __half2*)(gbuf + ((size_t)s1 << 7)) + lane);
        __half2 h2 = *((const __half2*)(gbuf + ((size_t)s2 << 7)) + lane);
        __half2 h3 = *((const __half2*)(gbuf + ((size_t)s3 << 7)) + lane);
        __half2 h4 = *((const __half2*)(gbuf + ((size_t)s4 << 7)) + lane);
        __half2 h5 = *((const __half2*)(gbuf + ((size_t)s5 << 7)) + lane);
        __half2 h6 = *((const __half2*)(gbuf + ((size_t)s6 << 7)) + lane);
        __half2 h7 = *((const __half2*)(gbuf + ((size_t)s7 << 7)) + lane);
        float2 v0 = __half22float2(h0), v1 = __half22float2(h1);
        float2 v2 = __half22float2(h2), v3 = __half22float2(h3);
        float2 v4 = __half22float2(h4), v5 = __half22float2(h5);
        float2 v6 = __half22float2(h6), v7 = __half22float2(h7);
        ax += ((v0.x + v1.x) + (v2.x + v3.x)) + ((v4.x + v5.x) + (v6.x + v7.x));
        ay += ((v0.y + v1.y) + (v2.y + v3.y)) + ((v4.y + v5.y) + (v6.y + v7.y));
    }
    for (; e < end; ++e) {
        int s = csr[e];
        float2 v = __half22float2(*((const __half2*)(gbuf + ((size_t)s << 7)) + lane));
        ax += v.x;
        ay += v.y;
    }
    float di = dis[node];
    ax = fmaf(di, ax, bias[lane * 2]);
    ay = fmaf(di, ay, bias[lane * 2 + 1]);
    if (RELU) { ax = fmaxf(ax, 0.f); ay = fmaxf(ay, 0.f); }
    *((float2*)(out + ((size_t)node << 7)) + lane) = make_float2(ax, ay);
}

// ---------------------------------------------------------------------------

extern "C" void kernel_launch(void* const* d_in, const int* in_sizes, int n_in,
                              void* d_out, int out_size, void* d_ws, size_t ws_size,
                              hipStream_t stream) {
    const float* x  = (const float*)d_in[0];
    const int*   ei = (const int*)d_in[1];   // [2][E]: src then dst
    const float* W1 = (const float*)d_in[2];
    const float* b1 = (const float*)d_in[3];
    const float* Wc = (const float*)d_in[4];
    const float* bc = (const float*)d_in[5];
    const float* W2 = (const float*)d_in[6];
    const float* b2 = (const float*)d_in[7];
    const float* Wo = (const float*)d_in[8];
    const float* bo = (const float*)d_in[9];
    float* out = (float*)d_out;

    // workspace carve-up (256B aligned)
    char* base = (char*)d_ws;
    auto carve = [&](size_t bytes) {
        void* p = (void*)base;
        base += (bytes + 255) & ~(size_t)255;
        return p;
    };
    // tmp region: counts8+pbase8 live during CSR build; W bf16 planes alias
    // it afterwards (prep_w launches after fill_csr_rank in stream order).
    char*  tmp      = (char*)carve(4 * 1024 * 1024);
    int*   counts8  = (int*)tmp;                        // 1.6 MB
    int*   pbase8   = (int*)(tmp + 2 * 1024 * 1024);    // 1.6 MB
    ushort* wplanes = (ushort*)tmp;                     // 320 KB, after fill
    int*   offsets  = (int*)carve((Nn + 1) * sizeof(int));
    int*   partials = (int*)carve(256 * sizeof(int));
    float* dis      = (float*)carve(Nn * sizeof(float));
    int*   rank     = (int*)carve((size_t)Ee * sizeof(int));
    int*   csr      = (int*)carve((size_t)Ee * sizeof(int));
    __half* gbuf    = (__half*)carve((size_t)Nn * 128 * sizeof(__half));
    float* bufB     = (float*)carve((size_t)Nn * 128 * sizeof(float));
    float* bufC     = (float*)carve((size_t)Nn * 128 * sizeof(float));

    const ushort* w1hi = wplanes;
    const ushort* w1lo = wplanes + 16384;
    const ushort* wchi = wplanes + 32768;
    const ushort* wclo = wplanes + 65536;
    const ushort* w2hi = wplanes + 98304;
    const ushort* w2lo = wplanes + 114688;
    const ushort* wohi = wplanes + 131072;
    const ushort* wolo = wplanes + 147456;

    const int SCAN_BLOCKS = (Nn + 255) / 256;  // 196
    const int EB = (Ee + 255) / 256;           // 6250

    // --- CSR build (atomic-free scatter via per-partition rank) ---
    hipMemsetAsync(counts8, 0, NPART * Nn * sizeof(int), stream);
    hist_rank_kernel<<<EB, 256, 0, stream>>>(ei + Ee, counts8, rank);
    scan1_kernel<<<SCAN_BLOCKS, 256, 0, stream>>>(counts8, offsets, partials);
    scan3_kernel<<<SCAN_BLOCKS, 256, 0, stream>>>(offsets, partials, counts8, pbase8, dis);
    fill_csr_rank<<<EB, 256, 0, stream>>>(ei, rank, pbase8, csr);

    // --- weight prep (aliases dead counts8 space) ---
    prep_w_kernel<<<320, 256, 0, stream>>>(W1, Wc, W2, Wo, (ushort*)wplanes);

    const int GB = (Nn + 63) / 64;   // 782
    const int PB = (Nn + 3) / 4;     // 12500

    // g1 = fp16( dis * (x @ W1^T) )             -> gbuf
    mfma_gemm<128, 128, false, false, true, true><<<GB, 512, 0, stream>>>(
        x, nullptr, w1hi, w1lo, nullptr, dis, gbuf);
    // x_agg = relu(dis*(sum g1) + b1)           -> bufB (f32)
    propagate_kernel<true><<<PB, 256, 0, stream>>>(gbuf, offsets, csr, dis, b1, bufB);
    // x_comb = relu([x_agg, x] @ Wc^T + bc)     -> bufC (f32)
    mfma_gemm<128, 256, true, true, false, false><<<GB, 512, 0, stream>>>(
        bufB, x, wchi, wclo, bc, nullptr, bufC);
    // g2 = fp16( dis * (x_comb @ W2^T) )        -> gbuf
    mfma_gemm<128, 128, false, false, true, true><<<GB, 512, 0, stream>>>(
        bufC, nullptr, w2hi, w2lo, nullptr, dis, gbuf);
    // agg2 = dis*(sum g2) + b2                  -> bufB (f32)
    propagate_kernel<false><<<PB, 256, 0, stream>>>(gbuf, offsets, csr, dis, b2, bufB);
    // out = [agg2, x_comb] @ Wo^T + bo          -> d_out
    mfma_gemm<64, 256, false, true, false, false><<<GB, 512, 0, stream>>>(
        bufB, bufC, wohi, wolo, bo, nullptr, out);
}